// Round 14
// baseline (311.690 us; speedup 1.0000x reference)
//
#include <hip/hip_runtime.h>
#include <math.h>

#define BB 8
#define CC 256
#define KK 19
#define HW 16384
#define HW4 4096            // HW / 4 (float4 units)

// ---- K1 history (13 rounds compressed) ----
// Staged-LDS family (r6 best: 5-row SGPR map + global_load_lds + swizzle):
//   K1 pinned at 75-85 us across DS volume (r7), drain count (r10),
//   occupancy 2x (r11), barriers {1,4,8} (r13/r6/r11) — all pipes <30%.
// r8 (direct per-lane rows): 134 us — lanes spanned 64 channel ROWS per
//   instruction = gather, TA-bound. r12 (19-row map): VMEM fallback at
//   VGPR=104, staging pipeline drained every j.
// r14 (this): K2-STYLE COALESCED STREAMING for K1. Lane l covers hw
//   position u*64+l (lanes span hw WITHIN a row — one 1KB run per load,
//   the pattern K2 proves at 6.9 TB/s). Per u: 5 map quads + 4 feature
//   quads + 80 FMAs into acc[5k][4c]. No LDS, no barriers, no SMEM, no
//   global_load_lds, no gather, no cross-lane reduce (lane dim becomes the
//   part 'e' axis; K1b folds it). Map re-read by 64 cg-blocks/(b,sh) ->
//   ~640 MB L2-served (cg = fastest grid dim so sharers co-dispatch).
//   VGPR: 20 acc + 20 m + 16 f + addr ~= 60 <= 64 (tell: WRITE_SIZE 40MB).

typedef float f32x4 __attribute__((ext_vector_type(4)));

#define FOR_K(OP) OP(0) OP(1) OP(2) OP(3) OP(4) OP(5) OP(6) OP(7) OP(8) OP(9) \
                  OP(10) OP(11) OP(12) OP(13) OP(14) OP(15) OP(16) OP(17) OP(18)

#define DOT(A, M, F) A += M.x * F.x + M.y * F.y + M.z * F.z + M.w * F.w;

__global__ __launch_bounds__(256) void CGM_k1_contract(
    const float* __restrict__ feature,
    const float* __restrict__ map_,
    float* __restrict__ att,        // fallback target (pre-zeroed)
    float* __restrict__ part)       // [KK][BB][CC][256] partials, or nullptr
{
    const int bI = blockIdx.x;      // ((b*4 + sh)*64 + cg), cg fastest
    const int cg = bI & 63;         // channel group: channels cg*4 .. cg*4+3
    const int sh = (bI >> 6) & 3;   // hw quarter: float4 posns [sh*1024, +1024)
    const int b  = bI >> 8;
    const int t  = threadIdx.x;
    const int l  = t & 63;          // lane: hw float4 position u*64 + l
    const int w  = t >> 6;          // wave id 0..3 -> k-group klo = 5w

    const int klo = w * 5;          // 0,5,10,15
    // 5th row: k=klo+4, except wave 3 re-loads k=18 (dup, never stored).
    const size_t k4row = (size_t)((w == 3) ? 3 : 4) * HW4;

    // All streams: wave-uniform base + per-lane offset (u*64+l)*16B ->
    // saddr-form global_load_dwordx4, perfectly coalesced 1KB per inst.
    const float4* mb = (const float4*)map_
                     + ((size_t)b * KK + klo) * HW4 + sh * 1024 + l;
    const float4* fb = (const float4*)feature
                     + ((size_t)b * CC + cg * 4) * HW4 + sh * 1024 + l;

    float a00 = 0.f, a01 = 0.f, a02 = 0.f, a03 = 0.f, a04 = 0.f;  // c0, k0..4
    float a10 = 0.f, a11 = 0.f, a12 = 0.f, a13 = 0.f, a14 = 0.f;  // c1
    float a20 = 0.f, a21 = 0.f, a22 = 0.f, a23 = 0.f, a24 = 0.f;  // c2
    float a30 = 0.f, a31 = 0.f, a32 = 0.f, a33 = 0.f, a34 = 0.f;  // c3

#pragma unroll 1
    for (int u = 0; u < 16; ++u) {
        const int off = u * 64;
        const float4 m0 = mb[off];
        const float4 m1 = mb[off + 1 * HW4];
        const float4 m2 = mb[off + 2 * HW4];
        const float4 m3 = mb[off + 3 * HW4];
        const float4 m4 = mb[off + k4row];
        const float4 f0 = fb[off];
        const float4 f1 = fb[off + 1 * HW4];
        const float4 f2 = fb[off + 2 * HW4];
        const float4 f3 = fb[off + 3 * HW4];
        DOT(a00, m0, f0) DOT(a01, m1, f0) DOT(a02, m2, f0)
        DOT(a03, m3, f0) DOT(a04, m4, f0)
        DOT(a10, m0, f1) DOT(a11, m1, f1) DOT(a12, m2, f1)
        DOT(a13, m3, f1) DOT(a14, m4, f1)
        DOT(a20, m0, f2) DOT(a21, m1, f2) DOT(a22, m2, f2)
        DOT(a23, m3, f2) DOT(a24, m4, f2)
        DOT(a30, m0, f3) DOT(a31, m1, f3) DOT(a32, m2, f3)
        DOT(a33, m3, f3) DOT(a34, m4, f3)
    }

    const int c0 = cg * 4;
    const int e  = sh * 64 + l;     // this lane's slot in the e axis (0..255)
    if (part) {
        // part[k][b][c][e]: lanes vary l -> consecutive e -> 256 B coalesced
        // stores, one per (k, c).
#define STK(KI, V0, V1, V2, V3) if (klo + (KI) < KK) {                   \
        float* d = part + (((size_t)(klo + (KI)) * BB + b) * CC + c0) * 256 + e; \
        d[0 * 256] = V0; d[1 * 256] = V1; d[2 * 256] = V2; d[3 * 256] = V3; }
        STK(0, a00, a10, a20, a30)
        STK(1, a01, a11, a21, a31)
        STK(2, a02, a12, a22, a32)
        STK(3, a03, a13, a23, a33)
        STK(4, a04, a14, a24, a34)
#undef STK
    } else {
        // Fallback: reduce within the wave is NOT done here; use atomics
        // per lane (128 adds/address over the kernel — pre-zeroed att).
#define STK(KI, V0, V1, V2, V3) if (klo + (KI) < KK) {                   \
        atomicAdd(&att[(size_t)(b * CC + c0 + 0) * KK + klo + (KI)], V0); \
        atomicAdd(&att[(size_t)(b * CC + c0 + 1) * KK + klo + (KI)], V1); \
        atomicAdd(&att[(size_t)(b * CC + c0 + 2) * KK + klo + (KI)], V2); \
        atomicAdd(&att[(size_t)(b * CC + c0 + 3) * KK + klo + (KI)], V3); }
        STK(0, a00, a10, a20, a30)
        STK(1, a01, a11, a21, a31)
        STK(2, a02, a12, a22, a32)
        STK(3, a03, a13, a23, a33)
        STK(4, a04, a14, a24, a34)
#undef STK
    }
}

// ---- K1b: fold the 256-wide e axis of part[k][b][c][e] into att. ----
// Grid = BB*KK blocks, 256 threads; thread t = channel c sums its own
// contiguous 1 KB row (64 sequential float4).
__global__ __launch_bounds__(256) void CGM_k1b_reduce(
    const float* __restrict__ part,
    float* __restrict__ att)
{
    const int bk = blockIdx.x;      // b*KK + k
    const int b  = bk / KK;
    const int k  = bk - b * KK;
    const int t  = threadIdx.x;     // channel

    const float4* p4 = (const float4*)(part
                     + (((size_t)k * BB + b) * CC + t) * 256);

    float4 a0 = {0.f, 0.f, 0.f, 0.f}, a1 = a0, a2 = a0, a3 = a0;
#pragma unroll 4
    for (int i = 0; i < 64; i += 4) {
        const float4 v0 = p4[i + 0];
        const float4 v1 = p4[i + 1];
        const float4 v2 = p4[i + 2];
        const float4 v3 = p4[i + 3];
        a0.x += v0.x; a0.y += v0.y; a0.z += v0.z; a0.w += v0.w;
        a1.x += v1.x; a1.y += v1.y; a1.z += v1.z; a1.w += v1.w;
        a2.x += v2.x; a2.y += v2.y; a2.z += v2.z; a2.w += v2.w;
        a3.x += v3.x; a3.y += v3.y; a3.z += v3.z; a3.w += v3.w;
    }
    const float sx = (a0.x + a1.x) + (a2.x + a3.x);
    const float sy = (a0.y + a1.y) + (a2.y + a3.y);
    const float sz = (a0.z + a1.z) + (a2.z + a3.z);
    const float sw = (a0.w + a1.w) + (a2.w + a3.w);
    att[(size_t)(b * CC + t) * KK + k] = (sx + sy) + (sz + sw);
}

// ---- K2: gate + apply (frozen since round 2) ----
#define S2 8                 // hw splits
#define CT2 16               // channels per block
#define CHUNK24 (HW4 / S2)   // 512 float4

__global__ __launch_bounds__(256) void CGM_k2_apply(
    const float* __restrict__ feature,
    const float* __restrict__ gamma,
    const float* __restrict__ att,
    float* __restrict__ out)
{
    const int bI = blockIdx.x;
    const int ct = bI & 15;
    const int s  = (bI >> 4) & (S2 - 1);
    const int b  = bI >> 7;
    const int t  = threadIdx.x;
    const int c0 = ct * CT2;

    __shared__ float sgk[CT2 * KK];
    __shared__ float scale[CT2];

    // NOTE: CT2*KK = 304 > 256 threads — MUST be a strided loop, not `if`.
    for (int idx = t; idx < CT2 * KK; idx += 256) {
        const int c = idx / KK;
        const int k = idx - c * KK;
        const float a = att[(size_t)(b * CC + c0 + c) * KK + k];
        const float sig = 1.f / (1.f + __expf(-a));
        sgk[idx] = sig * gamma[k];
    }
    __syncthreads();

    if (t < CT2) {
        float ssum = 0.f;
#define ADDK(K) ssum += sgk[t * KK + (K)];
        FOR_K(ADDK)
#undef ADDK
        scale[t] = 1.f + ssum;
    }
    __syncthreads();

    const float4* f4 = (const float4*)feature + (size_t)(b * CC + c0) * HW4;
    float4*       o4 = (float4*)out           + (size_t)(b * CC + c0) * HW4;
    const int ibase = s * CHUNK24;
#pragma unroll
    for (int c = 0; c < CT2; ++c) {
        const float sc = scale[c];
#pragma unroll
        for (int r = 0; r < CHUNK24 / 256; ++r) {   // 2 iterations
            const int i = ibase + r * 256 + t;
            const float4 f = f4[(size_t)c * HW4 + i];
            float4 o;
            o.x = f.x * sc;
            o.y = f.y * sc;
            o.z = f.z * sc;
            o.w = f.w * sc;
            o4[(size_t)c * HW4 + i] = o;
        }
    }
}

extern "C" void kernel_launch(void* const* d_in, const int* in_sizes, int n_in,
                              void* d_out, int out_size, void* d_ws, size_t ws_size,
                              hipStream_t stream) {
    const float* feature = (const float*)d_in[0];
    const float* map_    = (const float*)d_in[1];
    const float* gamma   = (const float*)d_in[2];
    float* out           = (float*)d_out;
    float* att           = (float*)d_ws;   // BB*CC*KK*4 = 155,648 B

    const size_t att_bytes  = (size_t)BB * CC * KK * sizeof(float);
    const size_t part_off   = (att_bytes + 255) & ~(size_t)255;
    const size_t part_bytes = (size_t)KK * BB * CC * 256 * sizeof(float); // 39,845,888 B
    const bool   split      = ws_size >= part_off + part_bytes;
    float* part = split ? (float*)((char*)d_ws + part_off) : nullptr;

    if (!split) {
        // att is re-poisoned to 0xAA before every launch — atomic fallback
        // needs it zeroed (hipMemsetAsync on stream is graph-capture safe).
        hipMemsetAsync(att, 0, att_bytes, stream);
    }

    const int grid1 = BB * 4 * 64;            // 2048: (b, sh) x cg, cg fastest
    CGM_k1_contract<<<grid1, 256, 0, stream>>>(feature, map_, att, part);

    if (split) {
        CGM_k1b_reduce<<<BB * KK, 256, 0, stream>>>(part, att);
    }

    const int grid2 = BB * S2 * (CC / CT2);   // 1024
    CGM_k2_apply<<<grid2, 256, 0, stream>>>(feature, gamma, att, out);
}